// Round 1
// baseline (109.883 us; speedup 1.0000x reference)
//
#include <hip/hip_runtime.h>

// IPN layer: per batch b, X = x[b] (64 rows x 32 cols, fp32).
// out[b, p] = dot(X[i], X[j]) for row-major strict-upper pairs (i<j), p packed.
// B=8192, F=64, E=32, PAIRS = 64*63/2 = 2016.
//
// One wave (64 lanes) handles one batch: stage 8KB of X into a wave-private
// LDS region (XOR-swizzled float4 layout to keep ds_read_b128 conflict-free),
// then each lane computes an 8x8 tile of the gram matrix (2 ds_read_b128 per
// pair amortized) and writes the valid strict-upper entries with forward-
// mapped packed offsets. No __syncthreads needed (LDS is wave-private).

#define FDIM 64
#define EDIM 32
#define PAIRS 2016

__global__ __launch_bounds__(256) void ipn_gram_kernel(const float* __restrict__ x,
                                                       float* __restrict__ out) {
    __shared__ float4 lds4[4][512];  // 4 waves * 64 rows * 8 float4 = 32 KiB

    const int tid  = threadIdx.x;
    const int w    = tid >> 6;
    const int lane = tid & 63;
    const int b    = blockIdx.x * 4 + w;

    // ---- stage batch b into LDS (swizzled) ----
    // global: row r, float4 slot e4 at xv[r*8 + e4]
    // lds   : row r, slot stored at (e4 ^ (r>>3))  -> bank-quad = e4 ^ (r>>3)
    const float4* xv = (const float4*)x + (size_t)b * 512;
    #pragma unroll
    for (int it = 0; it < 8; ++it) {
        float4 v = xv[it * 64 + lane];
        int r  = it * 8 + (lane >> 3);   // r>>3 == it
        int e4 = lane & 7;
        lds4[w][r * 8 + (e4 ^ it)] = v;
    }
    // (compiler inserts lgkmcnt waits; same-wave producer/consumer, no barrier)

    const int tr = lane >> 3;   // tile row: rows tr*8 .. tr*8+7
    const int tc = lane & 7;    // tile col: cols tc*8 .. tc*8+7

    float acc[8][8];
    #pragma unroll
    for (int k = 0; k < 8; ++k)
        #pragma unroll
        for (int m = 0; m < 8; ++m) acc[k][m] = 0.f;

    #pragma unroll
    for (int e4 = 0; e4 < 8; ++e4) {
        float4 a[8], bb[8];
        #pragma unroll
        for (int k = 0; k < 8; ++k)
            a[k] = lds4[w][(tr * 8 + k) * 8 + (e4 ^ tr)];
        #pragma unroll
        for (int k = 0; k < 8; ++k)
            bb[k] = lds4[w][(tc * 8 + k) * 8 + (e4 ^ tc)];
        #pragma unroll
        for (int k = 0; k < 8; ++k)
            #pragma unroll
            for (int m = 0; m < 8; ++m) {
                float s = acc[k][m];
                s = fmaf(a[k].x, bb[m].x, s);
                s = fmaf(a[k].y, bb[m].y, s);
                s = fmaf(a[k].z, bb[m].z, s);
                s = fmaf(a[k].w, bb[m].w, s);
                acc[k][m] = s;
            }
    }

    // ---- write packed strict-upper entries ----
    // off(i) = i*(127-i)/2 ; out idx = b*2016 + off(i) + (j - i - 1)
    float* ob = out + (size_t)b * PAIRS;
    #pragma unroll
    for (int k = 0; k < 8; ++k) {
        int i = tr * 8 + k;
        int base = i * (2 * FDIM - 1 - i) / 2 - i - 1;
        #pragma unroll
        for (int m = 0; m < 8; ++m) {
            int j = tc * 8 + m;
            if (j > i) ob[base + j] = acc[k][m];
        }
    }
}

extern "C" void kernel_launch(void* const* d_in, const int* in_sizes, int n_in,
                              void* d_out, int out_size, void* d_ws, size_t ws_size,
                              hipStream_t stream) {
    const float* x = (const float*)d_in[0];
    float* out = (float*)d_out;
    const int nb = in_sizes[0] / (FDIM * EDIM);   // 8192 batches
    const int grid = nb / 4;                      // 4 batches per block
    ipn_gram_kernel<<<grid, 256, 0, stream>>>(x, out);
}

// Round 2
// 27.057 us; speedup vs baseline: 4.0612x; 4.0612x over previous
//
#include <hip/hip_runtime.h>

// IPN layer: per batch b, X = x[b] (64 rows x 32 cols, fp32).
// out[b, p] = dot(X[i], X[j]) for row-major strict-upper pairs (i<j), packed.
// B=8192, F=64, E=32, PAIRS = 2016.
//
// MFMA formulation: gram tile (p,q) = mfma_f32_16x16x32_bf16(frag[p], frag[q]).
// For X·X^T the same lane-fragment (lane l holds X[blk*16 + (l&15)][(l>>4)*8 + t])
// is valid as BOTH the A operand (lane&15 = row i) and the B operand
// (lane&15 = col j of X^T, elements along k). One wave per batch, no LDS,
// no barriers; 10 upper-triangle tiles -> 40 acc VGPRs + 16 frag VGPRs.

#define FDIM 64
#define EDIM 32
#define PAIRS 2016

typedef __attribute__((ext_vector_type(8))) short bf16x8;
typedef __attribute__((ext_vector_type(4))) float f32x4;

static __device__ __forceinline__ short f2bf(float f) {
    union { float f; unsigned u; } v; v.f = f;
    unsigned r = v.u + 0x7FFFu + ((v.u >> 16) & 1u);   // RNE truncate to bf16
    return (short)(r >> 16);
}

__global__ __launch_bounds__(256, 4) void ipn_mfma_kernel(const float* __restrict__ x,
                                                          float* __restrict__ out) {
    const int tid = threadIdx.x;
    const int w   = tid >> 6;          // wave in block
    const int l   = tid & 63;          // lane
    const int b   = blockIdx.x * 4 + w;

    const int r16 = l & 15;            // row-within-16-block (also col for B role)
    const int kb  = (l >> 4) * 8;      // k-base for this lane

    const float* xb = x + (size_t)b * (FDIM * EDIM);

    // ---- load + convert the 4 row-block fragments ----
    bf16x8 frag[4];
    #pragma unroll
    for (int p = 0; p < 4; ++p) {
        const float* rp = xb + (p * 16 + r16) * EDIM + kb;
        float4 lo = *(const float4*)(rp);
        float4 hi = *(const float4*)(rp + 4);
        bf16x8 f;
        f[0] = f2bf(lo.x); f[1] = f2bf(lo.y); f[2] = f2bf(lo.z); f[3] = f2bf(lo.w);
        f[4] = f2bf(hi.x); f[5] = f2bf(hi.y); f[6] = f2bf(hi.z); f[7] = f2bf(hi.w);
        frag[p] = f;
    }

    // ---- 10 upper-triangle 16x16 tiles ----
    f32x4 acc[10];
    #pragma unroll
    for (int t = 0; t < 10; ++t) acc[t] = (f32x4)(0.0f);

    {
        int idx = 0;
        #pragma unroll
        for (int p = 0; p < 4; ++p) {
            #pragma unroll
            for (int q = p; q < 4; ++q) {
                acc[idx] = __builtin_amdgcn_mfma_f32_16x16x32_bf16(
                    frag[p], frag[q], acc[idx], 0, 0, 0);
                ++idx;
            }
        }
    }

    // ---- packed strict-upper write ----
    // C/D layout: col = lane&15, row = (lane>>4)*4 + reg   [m89]
    float* ob = out + (size_t)b * PAIRS;
    const int jc = r16;                // col within tile
    const int ir = (l >> 4) * 4;       // row base within tile
    {
        int idx = 0;
        #pragma unroll
        for (int p = 0; p < 4; ++p) {
            #pragma unroll
            for (int q = p; q < 4; ++q) {
                const int jg = q * 16 + jc;
                #pragma unroll
                for (int t = 0; t < 4; ++t) {
                    const int ig = p * 16 + ir + t;
                    if (p < q || jg > ig) {
                        // off(i) = i*(127-i)/2 ; entry (i,j) at off(i) + j - i - 1
                        const int base = ig * (2 * FDIM - 1 - ig) / 2 - ig - 1;
                        ob[base + jg] = acc[idx][t];
                    }
                }
                ++idx;
            }
        }
    }
}

extern "C" void kernel_launch(void* const* d_in, const int* in_sizes, int n_in,
                              void* d_out, int out_size, void* d_ws, size_t ws_size,
                              hipStream_t stream) {
    const float* x = (const float*)d_in[0];
    float* out = (float*)d_out;
    const int nb = in_sizes[0] / (FDIM * EDIM);   // 8192 batches
    const int grid = nb / 4;                      // 4 batches (waves) per block
    ipn_mfma_kernel<<<grid, 256, 0, stream>>>(x, out);
}

// Round 4
// 25.301 us; speedup vs baseline: 4.3430x; 1.0694x over previous
//
#include <hip/hip_runtime.h>

// IPN layer: per batch b, X = x[b] (64 rows x 32 cols, fp32).
// out[b, p] = dot(X[i], X[j]) for row-major strict-upper pairs (i<j), packed.
// B=8192, F=64, E=32, PAIRS = 2016.
//
// MFMA formulation: gram tile (p,q) = mfma_f32_16x16x32_bf16(frag[p], frag[q]).
// For X·X^T the same lane-fragment works as BOTH A and B operands.
// One wave per batch, no barriers.
//
// Epilogue: scatter the packed strict-upper values into a wave-private LDS
// buffer (ds_write_b32), then stream them out as dense aligned float4
// nontemporal stores (8064 B/batch = 504 float4, line-aligned).

#define FDIM 64
#define EDIM 32
#define PAIRS 2016

typedef __attribute__((ext_vector_type(8))) short bf16x8;
typedef __attribute__((ext_vector_type(4))) float f32x4;

static __device__ __forceinline__ short f2bf(float f) {
    union { float f; unsigned u; } v; v.f = f;
    unsigned r = v.u + 0x7FFFu + ((v.u >> 16) & 1u);   // RNE truncate to bf16
    return (short)(r >> 16);
}

__global__ __launch_bounds__(256, 4) void ipn_mfma_kernel(const float* __restrict__ x,
                                                          float* __restrict__ out) {
    __shared__ float pbuf[4][2048];    // 4 waves * 8 KiB packed-output staging

    const int tid = threadIdx.x;
    const int w   = tid >> 6;          // wave in block
    const int l   = tid & 63;          // lane
    const int b   = blockIdx.x * 4 + w;

    const int r16 = l & 15;            // row-within-16-block (also col for B role)
    const int kb  = (l >> 4) * 8;      // k-base for this lane

    const float* xb = x + (size_t)b * (FDIM * EDIM);

    // ---- load + convert the 4 row-block fragments ----
    bf16x8 frag[4];
    #pragma unroll
    for (int p = 0; p < 4; ++p) {
        const float* rp = xb + (p * 16 + r16) * EDIM + kb;
        f32x4 lo = *(const f32x4*)(rp);
        f32x4 hi = *(const f32x4*)(rp + 4);
        bf16x8 f;
        f[0] = f2bf(lo.x); f[1] = f2bf(lo.y); f[2] = f2bf(lo.z); f[3] = f2bf(lo.w);
        f[4] = f2bf(hi.x); f[5] = f2bf(hi.y); f[6] = f2bf(hi.z); f[7] = f2bf(hi.w);
        frag[p] = f;
    }

    // ---- 10 upper-triangle 16x16 tiles ----
    f32x4 acc[10];
    #pragma unroll
    for (int t = 0; t < 10; ++t) acc[t] = (f32x4)(0.0f);
    {
        int idx = 0;
        #pragma unroll
        for (int p = 0; p < 4; ++p)
            #pragma unroll
            for (int q = p; q < 4; ++q) {
                acc[idx] = __builtin_amdgcn_mfma_f32_16x16x32_bf16(
                    frag[p], frag[q], acc[idx], 0, 0, 0);
                ++idx;
            }
    }

    // ---- scatter packed values into wave-private LDS ----
    // C/D layout: col = lane&15, row = (lane>>4)*4 + reg   [m89]
    // packed pos(i,j) = i*(127-i)/2 + (j - i - 1)
    float* pb = pbuf[w];
    const int jc = r16;
    const int ir = (l >> 4) * 4;
    {
        int idx = 0;
        #pragma unroll
        for (int p = 0; p < 4; ++p)
            #pragma unroll
            for (int q = p; q < 4; ++q) {
                const int jg = q * 16 + jc;
                #pragma unroll
                for (int t = 0; t < 4; ++t) {
                    const int ig = p * 16 + ir + t;
                    if (p < q || jg > ig) {
                        const int base = ig * (2 * FDIM - 1 - ig) / 2 - ig - 1;
                        pb[base + jg] = acc[idx][t];
                    }
                }
                ++idx;
            }
    }
    // wave-private producer/consumer: lgkmcnt ordering only, no barrier

    // ---- dense nontemporal float4 stream-out (504 float4 per batch) ----
    const f32x4* pb4 = (const f32x4*)pb;
    f32x4* ob4 = (f32x4*)(out + (size_t)b * PAIRS);
    #pragma unroll
    for (int it = 0; it < 8; ++it) {
        const int idx4 = it * 64 + l;
        if (idx4 < 504) {
            f32x4 v = pb4[idx4];
            __builtin_nontemporal_store(v, ob4 + idx4);
        }
    }
}

extern "C" void kernel_launch(void* const* d_in, const int* in_sizes, int n_in,
                              void* d_out, int out_size, void* d_ws, size_t ws_size,
                              hipStream_t stream) {
    const float* x = (const float*)d_in[0];
    float* out = (float*)d_out;
    const int nb = in_sizes[0] / (FDIM * EDIM);   // 8192 batches
    const int grid = nb / 4;                      // 4 batches (waves) per block
    ipn_mfma_kernel<<<grid, 256, 0, stream>>>(x, out);
}

// Round 5
// 25.250 us; speedup vs baseline: 4.3519x; 1.0021x over previous
//
#include <hip/hip_runtime.h>

// IPN layer: per batch b, X = x[b] (64 rows x 32 cols, fp32).
// out[b, p] = dot(X[i], X[j]) for row-major strict-upper pairs (i<j), packed.
// B=8192, F=64, E=32, PAIRS = 2016.
//
// MFMA formulation: gram tile (p,q) = mfma_f32_16x16x32_bf16(frag[p], frag[q]);
// the same lane-fragment serves as both A and B for X·X^T. One wave per TWO
// batches, software-pipelined: both batches' global loads are issued up
// front, so batch1's load latency hides under batch0's compute/epilogue and
// there is only one store-drain per two batches. Grid = 1024 blocks = 4/CU,
// a single residency round (no block-boundary bubbles).
//
// Epilogue per batch: scatter packed strict-upper values into wave-private
// LDS, then stream out as dense aligned f32x4 nontemporal stores.

#define FDIM 64
#define EDIM 32
#define PAIRS 2016

typedef __attribute__((ext_vector_type(8))) short bf16x8;
typedef __attribute__((ext_vector_type(4))) float f32x4;

static __device__ __forceinline__ short f2bf(float f) {
    union { float f; unsigned u; } v; v.f = f;
    unsigned r = v.u + 0x7FFFu + ((v.u >> 16) & 1u);   // RNE truncate to bf16
    return (short)(r >> 16);
}

static __device__ __forceinline__ void load_frags(const float* __restrict__ xb,
                                                  int r16, int kb, bf16x8 frag[4]) {
    #pragma unroll
    for (int p = 0; p < 4; ++p) {
        const float* rp = xb + (p * 16 + r16) * EDIM + kb;
        f32x4 lo = *(const f32x4*)(rp);
        f32x4 hi = *(const f32x4*)(rp + 4);
        bf16x8 f;
        f[0] = f2bf(lo.x); f[1] = f2bf(lo.y); f[2] = f2bf(lo.z); f[3] = f2bf(lo.w);
        f[4] = f2bf(hi.x); f[5] = f2bf(hi.y); f[6] = f2bf(hi.z); f[7] = f2bf(hi.w);
        frag[p] = f;
    }
}

static __device__ __forceinline__ void compute_store(const bf16x8 frag[4],
                                                     float* __restrict__ pb,
                                                     float* __restrict__ ob,
                                                     int l) {
    f32x4 acc[10];
    #pragma unroll
    for (int t = 0; t < 10; ++t) acc[t] = (f32x4)(0.0f);
    {
        int idx = 0;
        #pragma unroll
        for (int p = 0; p < 4; ++p)
            #pragma unroll
            for (int q = p; q < 4; ++q) {
                acc[idx] = __builtin_amdgcn_mfma_f32_16x16x32_bf16(
                    frag[p], frag[q], acc[idx], 0, 0, 0);
                ++idx;
            }
    }

    // scatter packed values into wave-private LDS
    // C/D layout: col = lane&15, row = (lane>>4)*4 + reg   [m89]
    const int jc = l & 15;
    const int ir = (l >> 4) * 4;
    {
        int idx = 0;
        #pragma unroll
        for (int p = 0; p < 4; ++p)
            #pragma unroll
            for (int q = p; q < 4; ++q) {
                const int jg = q * 16 + jc;
                #pragma unroll
                for (int t = 0; t < 4; ++t) {
                    const int ig = p * 16 + ir + t;
                    if (p < q || jg > ig) {
                        const int base = ig * (2 * FDIM - 1 - ig) / 2 - ig - 1;
                        pb[base + jg] = acc[idx][t];
                    }
                }
                ++idx;
            }
    }
    // wave-private producer/consumer: compiler's lgkmcnt ordering, no barrier

    // dense nontemporal f32x4 stream-out (504 float4 per batch)
    const f32x4* pb4 = (const f32x4*)pb;
    f32x4* ob4 = (f32x4*)ob;
    #pragma unroll
    for (int it = 0; it < 8; ++it) {
        const int idx4 = it * 64 + l;
        if (idx4 < 504) {
            f32x4 v = pb4[idx4];
            __builtin_nontemporal_store(v, ob4 + idx4);
        }
    }
}

__global__ __launch_bounds__(256, 4) void ipn_mfma_kernel(const float* __restrict__ x,
                                                          float* __restrict__ out) {
    __shared__ float pbuf[4][2048];    // 4 waves * 8 KiB packed-output staging

    const int tid = threadIdx.x;
    const int w   = tid >> 6;          // wave in block
    const int l   = tid & 63;          // lane
    const int bw  = blockIdx.x * 4 + w;
    const int b0  = bw * 2;            // this wave's two batches
    const int b1  = b0 + 1;

    const int r16 = l & 15;
    const int kb  = (l >> 4) * 8;

    // issue BOTH batches' loads up front (independent -> compiler hoists)
    bf16x8 frag0[4], frag1[4];
    load_frags(x + (size_t)b0 * (FDIM * EDIM), r16, kb, frag0);
    load_frags(x + (size_t)b1 * (FDIM * EDIM), r16, kb, frag1);

    float* pb = pbuf[w];
    compute_store(frag0, pb, out + (size_t)b0 * PAIRS, l);
    compute_store(frag1, pb, out + (size_t)b1 * PAIRS, l);
}

extern "C" void kernel_launch(void* const* d_in, const int* in_sizes, int n_in,
                              void* d_out, int out_size, void* d_ws, size_t ws_size,
                              hipStream_t stream) {
    const float* x = (const float*)d_in[0];
    float* out = (float*)d_out;
    const int nb = in_sizes[0] / (FDIM * EDIM);   // 8192 batches
    const int grid = nb / 8;                      // 4 waves/block * 2 batches/wave
    ipn_mfma_kernel<<<grid, 256, 0, stream>>>(x, out);
}